// Round 9
// baseline (511.913 us; speedup 1.0000x reference)
//
#include <hip/hip_runtime.h>
#include <hip/hip_bf16.h>
#include <math.h>

#define N_USERS   100000
#define N_RECIPES 50000
#define NE        600000
#define NL        200000
#define DU        128
#define DR        256
#define H         128
#define OUT_D     64

// CSR binning: 256 buckets per direction; bucket == one phase2-WG node range
#define NBKT 256
#define NB_R 196   // ceil(50000/256)
#define NB_U 391   // ceil(100000/256)

using half2v = __attribute__((ext_vector_type(2))) _Float16;
using half4v = __attribute__((ext_vector_type(4))) _Float16;
using half8v = __attribute__((ext_vector_type(8))) _Float16;
using f32x4  = __attribute__((ext_vector_type(4))) float;

__device__ __forceinline__ int wave_incl_scan(int v, int lane) {
#pragma unroll
  for (int o = 1; o < 64; o <<= 1) {
    int t = __shfl_up(v, o, 64);
    if (lane >= o) v += t;
  }
  return v;
}

// ---------------- batched f32 -> fp16 conversion (weights + features, + btot zero) ----------------
struct CPack {
  const float* src[12];
  _Float16* dst[12];
  int n4[12];  // element count / 4
  int* btot;   // [512] zeroed by block (0, y=0)
};
__global__ __launch_bounds__(256) void convert_all(CPack p) {
  const int m = blockIdx.y;
  if (m == 0 && blockIdx.x == 0) {
    p.btot[threadIdx.x] = 0;
    p.btot[threadIdx.x + 256] = 0;
  }
  const int n = p.n4[m];
  const float4* __restrict__ s = (const float4*)p.src[m];
  half4v* __restrict__ d = (half4v*)p.dst[m];
  for (int i = blockIdx.x * 256 + threadIdx.x; i < n; i += gridDim.x * 256) {
    float4 v = s[i];
    half4v h;
    h[0] = (_Float16)v.x; h[1] = (_Float16)v.y;
    h[2] = (_Float16)v.z; h[3] = (_Float16)v.w;
    d[i] = h;
  }
}

// ---------------- CSR phase 0: per-bucket totals (both directions) ----------------
__global__ __launch_bounds__(256) void csr_phase0(const int* __restrict__ esrc,
                                                  const int* __restrict__ edst,
                                                  int* __restrict__ btot) {
  __shared__ int h[512];
  const int tid = threadIdx.x;
  h[tid] = 0; h[tid + 256] = 0;
  __syncthreads();
  for (int i = blockIdx.x * 256 + tid; i < NE; i += gridDim.x * 256) {
    atomicAdd(&h[edst[i] / NB_R], 1);
    atomicAdd(&h[256 + esrc[i] / NB_U], 1);
  }
  __syncthreads();
  if (h[tid]) atomicAdd(&btot[tid], h[tid]);
  if (h[tid + 256]) atomicAdd(&btot[tid + 256], h[tid + 256]);
}

// ---------------- CSR bucket scan: bases + cursors (1 WG) ----------------
__global__ void csr_bscan(const int* __restrict__ btot,
                          int* __restrict__ bbase_r, int* __restrict__ bcur_r,
                          int* __restrict__ off_r,
                          int* __restrict__ bbase_u, int* __restrict__ bcur_u,
                          int* __restrict__ off_u) {
  __shared__ int wsum[4];
  const int tid = threadIdx.x, lane = tid & 63, wid = tid >> 6;
#pragma unroll
  for (int dir = 0; dir < 2; ++dir) {
    int v = btot[dir * 256 + tid];
    int inc = wave_incl_scan(v, lane);
    if (lane == 63) wsum[wid] = inc;
    __syncthreads();
    int woff = 0;
#pragma unroll
    for (int w = 0; w < 4; ++w)
      if (w < wid) woff += wsum[w];
    int excl = woff + inc - v;
    int* bbase = dir ? bbase_u : bbase_r;
    int* bcur = dir ? bcur_u : bcur_r;
    bbase[tid] = excl;
    bcur[tid] = excl;
    if (tid == 255) bbase[256] = excl + v;  // == NE
    __syncthreads();
  }
  if (tid == 0) {
    off_r[N_RECIPES] = NE;
    off_u[N_USERS] = NE;
  }
}

// ---------------- CSR phase 1: bin packed pairs into bucket regions ----------------
// packed = (local_node << 17) | payload   (payload < 2^17, local < 512)
__global__ __launch_bounds__(256) void csr_phase1(
    const int* __restrict__ esrc, const int* __restrict__ edst,
    int* __restrict__ bcur_r, int* __restrict__ bcur_u,
    unsigned* __restrict__ stage_r, unsigned* __restrict__ stage_u) {
  __shared__ int cnt[512];
  __shared__ int gbase[512];
  constexpr int EPT = 8;
  const int BATCH = 256 * EPT;
  const int tid = threadIdx.x;
  for (int base = blockIdx.x * BATCH; base < NE; base += gridDim.x * BATCH) {
    cnt[tid] = 0; cnt[tid + 256] = 0;
    __syncthreads();
    int s_[EPT], d_[EPT], rr_[EPT], ru_[EPT];
#pragma unroll
    for (int e = 0; e < EPT; ++e) {
      const int i = base + e * 256 + tid;
      if (i < NE) {
        const int s = esrc[i], d = edst[i];
        s_[e] = s; d_[e] = d;
        rr_[e] = atomicAdd(&cnt[d / NB_R], 1);
        ru_[e] = atomicAdd(&cnt[256 + s / NB_U], 1);
      } else {
        d_[e] = -1;
      }
    }
    __syncthreads();
    if (cnt[tid]) gbase[tid] = atomicAdd(&bcur_r[tid], cnt[tid]);
    if (cnt[tid + 256]) gbase[tid + 256] = atomicAdd(&bcur_u[tid], cnt[tid + 256]);
    __syncthreads();
#pragma unroll
    for (int e = 0; e < EPT; ++e) {
      if (d_[e] >= 0) {
        const int br = d_[e] / NB_R, lr = d_[e] - br * NB_R;
        stage_r[gbase[br] + rr_[e]] = ((unsigned)lr << 17) | (unsigned)s_[e];
        const int bu = s_[e] / NB_U, lu = s_[e] - bu * NB_U;
        stage_u[gbase[256 + bu] + ru_[e]] = ((unsigned)lu << 17) | (unsigned)d_[e];
      }
    }
    __syncthreads();
  }
}

// ---------------- CSR phase 2: one WG per bucket -> offx + eidx ----------------
template <int Nv, int NBv>
__device__ __forceinline__ void phase2_impl(int* cnt, int* wsum,
                                            const unsigned* __restrict__ stage,
                                            const int* __restrict__ bbase,
                                            int* __restrict__ offx,
                                            int* __restrict__ eidx, int B) {
  const int tid = threadIdx.x, lane = tid & 63, wid = tid >> 6;
  const int n0 = B * NBv;
  const int nloc = min(NBv, Nv - n0);
  cnt[tid] = 0; cnt[tid + 256] = 0;
  __syncthreads();
  const int s = bbase[B], e = bbase[B + 1];
  for (int i = s + tid; i < e; i += 256)
    atomicAdd(&cnt[stage[i] >> 17], 1);
  __syncthreads();
  const int e0 = cnt[2 * tid], e1 = cnt[2 * tid + 1];
  const int ssum = e0 + e1;
  int inc = wave_incl_scan(ssum, lane);
  if (lane == 63) wsum[wid] = inc;
  __syncthreads();
  int woff = 0;
#pragma unroll
  for (int w = 0; w < 4; ++w)
    if (w < wid) woff += wsum[w];
  const int base = s + woff + inc - ssum;  // absolute CSR offset of slot 2*tid
  if (2 * tid < nloc) offx[n0 + 2 * tid] = base;
  if (2 * tid + 1 < nloc) offx[n0 + 2 * tid + 1] = base + e0;
  cnt[2 * tid] = base;
  cnt[2 * tid + 1] = base + e0;
  __syncthreads();
  for (int i = s + tid; i < e; i += 256) {
    const unsigned p = stage[i];
    const int pos = atomicAdd(&cnt[p >> 17], 1);
    eidx[pos] = (int)(p & 0x1FFFFu);
  }
}

__global__ __launch_bounds__(256) void csr_phase2(
    const unsigned* __restrict__ stage_r, const int* __restrict__ bbase_r,
    int* __restrict__ off_r, int* __restrict__ eidx_r,
    const unsigned* __restrict__ stage_u, const int* __restrict__ bbase_u,
    int* __restrict__ off_u, int* __restrict__ eidx_u) {
  __shared__ int cnt[512];
  __shared__ int wsum[4];
  if (blockIdx.x < NBKT)
    phase2_impl<N_RECIPES, NB_R>(cnt, wsum, stage_r, bbase_r, off_r, eidx_r, blockIdx.x);
  else
    phase2_impl<N_USERS, NB_U>(cnt, wsum, stage_u, bbase_u, off_u, eidx_u, blockIdx.x - NBKT);
}

// ---------------- segment mean: L=ROWH/8 lanes per node, half8v loads ----------------
template <int ROWH, bool ADD, bool DORELU>
__global__ __launch_bounds__(256) void agg_mean2(
    const _Float16* __restrict__ feat, const int* __restrict__ offx,
    const int* __restrict__ eidx, _Float16* __restrict__ outm, int n_dst) {
  constexpr int L = ROWH / 8;
  const int nid = (int)((blockIdx.x * 256 + threadIdx.x) / L);
  const int ln = threadIdx.x & (L - 1);
  if (nid >= n_dst) return;
  const int s = offx[nid], e = offx[nid + 1];
  float a0[8] = {0}, a1[8] = {0}, a2[8] = {0}, a3[8] = {0};
  int i = s;
  for (; i + 3 < e; i += 4) {
    const int r0 = eidx[i], r1 = eidx[i + 1], r2 = eidx[i + 2], r3 = eidx[i + 3];
    half8v v0 = ((const half8v*)(feat + (size_t)r0 * ROWH))[ln];
    half8v v1 = ((const half8v*)(feat + (size_t)r1 * ROWH))[ln];
    half8v v2 = ((const half8v*)(feat + (size_t)r2 * ROWH))[ln];
    half8v v3 = ((const half8v*)(feat + (size_t)r3 * ROWH))[ln];
#pragma unroll
    for (int t = 0; t < 8; ++t) {
      a0[t] += (float)v0[t];
      a1[t] += (float)v1[t];
      a2[t] += (float)v2[t];
      a3[t] += (float)v3[t];
    }
  }
  for (; i < e; ++i) {
    const int r0 = eidx[i];
    half8v v0 = ((const half8v*)(feat + (size_t)r0 * ROWH))[ln];
#pragma unroll
    for (int t = 0; t < 8; ++t) a0[t] += (float)v0[t];
  }
  const float invc = (e > s) ? 1.f / (float)(e - s) : 0.f;
  half8v o, old;
  if (ADD) old = ((const half8v*)(outm + (size_t)nid * ROWH))[ln];
#pragma unroll
  for (int t = 0; t < 8; ++t) {
    float m = (a0[t] + a1[t] + a2[t] + a3[t]) * invc;
    if (ADD) m += (float)old[t];
    if (DORELU) m = fmaxf(m, 0.f);
    o[t] = (_Float16)m;
  }
  ((half8v*)(outm + (size_t)nid * ROWH))[ln] = o;
}

// ---------------- dual-table segment mean (conv2: both directions, ROWH=64) ----------------
__global__ __launch_bounds__(256) void agg_mean_dual64(
    const _Float16* __restrict__ fA, const int* __restrict__ offA,
    const int* __restrict__ eA, _Float16* __restrict__ oA,
    const _Float16* __restrict__ fB, const int* __restrict__ offB,
    const int* __restrict__ eB, _Float16* __restrict__ oB) {
  const int gnid = (int)((blockIdx.x * 256 + threadIdx.x) >> 3);
  const int ln = threadIdx.x & 7;
  if (gnid >= N_RECIPES + N_USERS) return;
  const _Float16* feat;
  const int* offx;
  const int* eidx;
  _Float16* outm;
  int nid;
  if (gnid < N_RECIPES) {
    feat = fA; offx = offA; eidx = eA; outm = oA; nid = gnid;
  } else {
    feat = fB; offx = offB; eidx = eB; outm = oB; nid = gnid - N_RECIPES;
  }
  const int s = offx[nid], e = offx[nid + 1];
  float a0[8] = {0}, a1[8] = {0}, a2[8] = {0}, a3[8] = {0};
  int i = s;
  for (; i + 3 < e; i += 4) {
    const int r0 = eidx[i], r1 = eidx[i + 1], r2 = eidx[i + 2], r3 = eidx[i + 3];
    half8v v0 = ((const half8v*)(feat + (size_t)r0 * OUT_D))[ln];
    half8v v1 = ((const half8v*)(feat + (size_t)r1 * OUT_D))[ln];
    half8v v2 = ((const half8v*)(feat + (size_t)r2 * OUT_D))[ln];
    half8v v3 = ((const half8v*)(feat + (size_t)r3 * OUT_D))[ln];
#pragma unroll
    for (int t = 0; t < 8; ++t) {
      a0[t] += (float)v0[t];
      a1[t] += (float)v1[t];
      a2[t] += (float)v2[t];
      a3[t] += (float)v3[t];
    }
  }
  for (; i < e; ++i) {
    const int r0 = eidx[i];
    half8v v0 = ((const half8v*)(feat + (size_t)r0 * OUT_D))[ln];
#pragma unroll
    for (int t = 0; t < 8; ++t) a0[t] += (float)v0[t];
  }
  const float invc = (e > s) ? 1.f / (float)(e - s) : 0.f;
  half8v old = ((const half8v*)(outm + (size_t)nid * OUT_D))[ln];
  half8v o;
#pragma unroll
  for (int t = 0; t < 8; ++t)
    o[t] = (_Float16)((a0[t] + a1[t] + a2[t] + a3[t]) * invc + (float)old[t]);
  ((half8v*)(outm + (size_t)nid * OUT_D))[ln] = o;
}

// ---------------- multi-part MFMA GEMM, compile-time K=128 inner passes ----------------
// Per part: out = [relu]( A1*W1^T [+ A2*W2^T] [+ bias] ), K = np*128, fp16 A/W.
// All 32 fragment loads of a 128-wide K-pass issued before the 64 MFMAs -> deep MLP.
struct GParts {
  const _Float16* A1[4];
  const _Float16* W1[4];
  const _Float16* A2[4];
  const _Float16* W2[4];
  const float* bias[4];
  _Float16* out[4];
  int M[4];
  int np1[4];
  int np2[4];
  int relu[4];
  int blk0[4];  // start block; unused -> 0x7fffffff
};

__device__ __forceinline__ void gemm_accum_k128(
    const _Float16* __restrict__ A, const _Float16* __restrict__ W, int np,
    const int arow[4], const int wrow[4], int lkb, f32x4 (&acc)[4][4]) {
  const int Kt = np << 7;
  for (int kp = 0; kp < np; ++kp) {
    half8v af[4][4], bf[4][4];
#pragma unroll
    for (int ks = 0; ks < 4; ++ks) {
      const int ko = (kp << 7) + ks * 32 + lkb;
#pragma unroll
      for (int i = 0; i < 4; ++i)
        af[ks][i] = *(const half8v*)(A + (size_t)arow[i] * Kt + ko);
#pragma unroll
      for (int j = 0; j < 4; ++j)
        bf[ks][j] = *(const half8v*)(W + (size_t)wrow[j] * Kt + ko);
    }
#pragma unroll
    for (int ks = 0; ks < 4; ++ks)
#pragma unroll
      for (int i = 0; i < 4; ++i)
#pragma unroll
        for (int j = 0; j < 4; ++j)
          acc[i][j] = __builtin_amdgcn_mfma_f32_16x16x32_f16(af[ks][i], bf[ks][j],
                                                             acc[i][j], 0, 0, 0);
  }
}

template <int BN>
__global__ __launch_bounds__(256) void gemm_parts(GParts P) {
  constexpr int WN = BN / 64;
  constexpr int BM = (4 / WN) * 64;  // 128 for BN=128, 256 for BN=64
  const int bid = blockIdx.x;
  const int p = (bid >= P.blk0[1]) + (bid >= P.blk0[2]) + (bid >= P.blk0[3]);
  const int M = P.M[p];
  const int m0 = (bid - P.blk0[p]) * BM;
  const int lane = threadIdx.x & 63;
  const int wid = threadIdx.x >> 6;
  const int wm = wid / WN;
  const int wn = wid % WN;
  const int lm = lane & 15;
  const int lkb = (lane >> 4) * 8;

  int arow[4];
#pragma unroll
  for (int i = 0; i < 4; ++i) {
    int r = m0 + wm * 64 + i * 16 + lm;
    arow[i] = (r < M) ? r : (M - 1);  // clamped rows never stored
  }
  int wrow[4];
#pragma unroll
  for (int j = 0; j < 4; ++j) wrow[j] = wn * 64 + j * 16 + lm;

  f32x4 acc[4][4];
  const f32x4 zero4 = {0.f, 0.f, 0.f, 0.f};
#pragma unroll
  for (int i = 0; i < 4; ++i)
#pragma unroll
    for (int j = 0; j < 4; ++j) acc[i][j] = zero4;

  gemm_accum_k128(P.A1[p], P.W1[p], P.np1[p], arow, wrow, lkb, acc);
  const int np2 = P.np2[p];
  if (np2 > 0) gemm_accum_k128(P.A2[p], P.W2[p], np2, arow, wrow, lkb, acc);

  // epilogue: optional bias / relu, fp16 store. C layout: col=lane&15, row=(lane>>4)*4+reg
  const float* __restrict__ bias = P.bias[p];
  const int dorelu = P.relu[p];
  _Float16* __restrict__ outp = P.out[p];
  const int rb = (lane >> 4) * 4;
#pragma unroll
  for (int j = 0; j < 4; ++j) {
    const int col = wrow[j];
    const float bj = bias ? bias[col] : 0.f;
#pragma unroll
    for (int i = 0; i < 4; ++i) {
#pragma unroll
      for (int r = 0; r < 4; ++r) {
        const int grow = m0 + wm * 64 + i * 16 + rb + r;
        if (grow < M) {
          float v = acc[i][j][r] + bj;
          if (dorelu) v = fmaxf(v, 0.f);
          outp[(size_t)grow * BN + col] = (_Float16)v;
        }
      }
    }
  }
}

// ---------------- decoder: one wave per label pair ----------------
__global__ __launch_bounds__(256) void decoder_f16(
    const _Float16* __restrict__ zu, const _Float16* __restrict__ zr,
    const int* __restrict__ ls, const int* __restrict__ ld,
    float* __restrict__ outp) {
  const int w = (blockIdx.x * 256 + threadIdx.x) >> 6;
  if (w >= NL) return;
  const int lane = threadIdx.x & 63;
  const int hl = lane & 31;
  const _Float16* src = (lane >= 32) ? (zr + (size_t)ld[w] * OUT_D)
                                     : (zu + (size_t)ls[w] * OUT_D);
  half2v v = ((const half2v*)src)[hl];
  float x0 = (float)v[0], x1 = (float)v[1];
  float y0 = __shfl_xor(x0, 32, 64);
  float y1 = __shfl_xor(x1, 32, 64);
  float nx = x0 * x0 + x1 * x1;
  float ny = y0 * y0 + y1 * y1;
  float ab = x0 * y0 + x1 * y1;
#pragma unroll
  for (int o = 16; o > 0; o >>= 1) {
    nx += __shfl_xor(nx, o, 64);
    ny += __shfl_xor(ny, o, 64);
    ab += __shfl_xor(ab, o, 64);
  }
  if (lane == 0) {
    float denom = fmaxf(sqrtf(nx), 1e-12f) * fmaxf(sqrtf(ny), 1e-12f);
    outp[w] = ab / denom;
  }
}

extern "C" void kernel_launch(void* const* d_in, const int* in_sizes, int n_in,
                              void* d_out, int out_size, void* d_ws, size_t ws_size,
                              hipStream_t stream) {
  (void)in_sizes; (void)n_in; (void)out_size; (void)ws_size;
  const float* x_user   = (const float*)d_in[0];
  const float* x_recipe = (const float*)d_in[1];
  const int* edge_src   = (const int*)d_in[2];
  const int* edge_dst   = (const int*)d_in[3];
  const int* lbl_src    = (const int*)d_in[4];
  const int* lbl_dst    = (const int*)d_in[5];
  const float* Wu       = (const float*)d_in[6];
  const float* bu       = (const float*)d_in[7];
  const float* Wrec     = (const float*)d_in[8];
  const float* brec     = (const float*)d_in[9];
  const float* c1_ur_Wl = (const float*)d_in[10];
  const float* c1_ur_bl = (const float*)d_in[11];
  const float* c1_ur_Wr = (const float*)d_in[12];
  const float* c1_ru_Wl = (const float*)d_in[13];
  const float* c1_ru_bl = (const float*)d_in[14];
  const float* c1_ru_Wr = (const float*)d_in[15];
  const float* c2_ur_Wl = (const float*)d_in[16];
  const float* c2_ur_bl = (const float*)d_in[17];
  const float* c2_ur_Wr = (const float*)d_in[18];
  const float* c2_ru_Wl = (const float*)d_in[19];
  const float* c2_ru_bl = (const float*)d_in[20];
  const float* c2_ru_Wr = (const float*)d_in[21];
  float* out = (float*)d_out;

  char* ws = (char*)d_ws;
  size_t off = 0;
  auto take = [&](size_t bytes) -> void* {
    void* p = ws + off;
    off = (off + bytes + 255) & ~(size_t)255;
    return p;
  };
  _Float16* hu    = (_Float16*)take((size_t)N_USERS * H * 2);    // 25.6 MB
  _Float16* hr    = (_Float16*)take((size_t)N_RECIPES * H * 2);  // 12.8 MB
  _Float16* meanr = (_Float16*)take((size_t)N_RECIPES * H * 2);  // 12.8 MB
  _Float16* r1    = (_Float16*)take((size_t)N_RECIPES * H * 2);
  _Float16* u1    = (_Float16*)take((size_t)N_USERS * H * 2);
  _Float16* t_r1  = (_Float16*)take((size_t)N_RECIPES * H * 2);  // dedicated (same-dispatch as meanr reads)
  _Float16* xu_h  = (_Float16*)take((size_t)N_USERS * DU * 2);   // 25.6 MB
  _Float16* xr_h  = (_Float16*)take((size_t)N_RECIPES * DR * 2); // 25.6 MB
  int* off_r  = (int*)take((size_t)(N_RECIPES + 1) * 4);
  int* off_u  = (int*)take((size_t)(N_USERS + 1) * 4);
  int* eidx_r = (int*)take((size_t)NE * 4);
  int* eidx_u = (int*)take((size_t)NE * 4);
  unsigned* stage_r = (unsigned*)take((size_t)NE * 4);
  unsigned* stage_u = (unsigned*)take((size_t)NE * 4);
  int* btot    = (int*)take(512 * 4);
  int* bbase_r = (int*)take(257 * 4);
  int* bbase_u = (int*)take(257 * 4);
  int* bcur_r  = (int*)take(256 * 4);
  int* bcur_u  = (int*)take(256 * 4);
  _Float16* Wu_h     = (_Float16*)take(H * DU * 2);
  _Float16* Wrec_h   = (_Float16*)take(H * DR * 2);
  _Float16* c1urWl_h = (_Float16*)take(H * H * 2);
  _Float16* c1urWr_h = (_Float16*)take(H * H * 2);
  _Float16* c1ruWl_h = (_Float16*)take(H * H * 2);
  _Float16* c1ruWr_h = (_Float16*)take(H * H * 2);
  _Float16* c2urWl_h = (_Float16*)take(OUT_D * H * 2);
  _Float16* c2urWr_h = (_Float16*)take(OUT_D * H * 2);
  _Float16* c2ruWl_h = (_Float16*)take(OUT_D * H * 2);
  _Float16* c2ruWr_h = (_Float16*)take(OUT_D * H * 2);
  // dead-buffer aliases (verified across dispatch boundaries):
  _Float16* t_u2 = hr;                              // hr last read: conv1 launch
  _Float16* t_r2 = meanr;                           // meanr last read: conv1 launch part0
  _Float16* zr   = hu;                              // hu last read: conv1 launch part2
  _Float16* zu   = hu + (size_t)N_RECIPES * OUT_D;  // disjoint from zr within hu region

  // ---- 1. f32->fp16 conversion: weights + input features (+ btot zero)
  CPack cp;
  cp.src[0] = x_user;   cp.dst[0] = xu_h;      cp.n4[0] = N_USERS * DU / 4;
  cp.src[1] = x_recipe; cp.dst[1] = xr_h;      cp.n4[1] = N_RECIPES * DR / 4;
  cp.src[2] = Wu;       cp.dst[2] = Wu_h;      cp.n4[2] = H * DU / 4;
  cp.src[3] = Wrec;     cp.dst[3] = Wrec_h;    cp.n4[3] = H * DR / 4;
  cp.src[4] = c1_ur_Wl; cp.dst[4] = c1urWl_h;  cp.n4[4] = H * H / 4;
  cp.src[5] = c1_ur_Wr; cp.dst[5] = c1urWr_h;  cp.n4[5] = H * H / 4;
  cp.src[6] = c1_ru_Wl; cp.dst[6] = c1ruWl_h;  cp.n4[6] = H * H / 4;
  cp.src[7] = c1_ru_Wr; cp.dst[7] = c1ruWr_h;  cp.n4[7] = H * H / 4;
  cp.src[8] = c2_ur_Wl; cp.dst[8] = c2urWl_h;  cp.n4[8] = OUT_D * H / 4;
  cp.src[9] = c2_ur_Wr; cp.dst[9] = c2urWr_h;  cp.n4[9] = OUT_D * H / 4;
  cp.src[10] = c2_ru_Wl; cp.dst[10] = c2ruWl_h; cp.n4[10] = OUT_D * H / 4;
  cp.src[11] = c2_ru_Wr; cp.dst[11] = c2ruWr_h; cp.n4[11] = OUT_D * H / 4;
  cp.btot = btot;
  convert_all<<<dim3(512, 12), 256, 0, stream>>>(cp);

  // ---- 2-5. CSR build
  csr_phase0<<<512, 256, 0, stream>>>(edge_src, edge_dst, btot);
  csr_bscan<<<1, 256, 0, stream>>>(btot, bbase_r, bcur_r, off_r, bbase_u, bcur_u, off_u);
  csr_phase1<<<(NE + 2047) / 2048, 256, 0, stream>>>(edge_src, edge_dst, bcur_r, bcur_u,
                                                     stage_r, stage_u);
  csr_phase2<<<2 * NBKT, 256, 0, stream>>>(stage_r, bbase_r, off_r, eidx_r,
                                           stage_u, bbase_u, off_u, eidx_u);

  auto clear_parts = [](GParts& P, int from) {
    for (int q = from; q < 4; ++q) {
      P.A1[q] = P.A2[q] = nullptr; P.W1[q] = P.W2[q] = nullptr;
      P.bias[q] = nullptr; P.out[q] = nullptr;
      P.M[q] = 1; P.np1[q] = 0; P.np2[q] = 0; P.relu[q] = 0;
      P.blk0[q] = 0x7fffffff;
    }
  };

  // ---- 6. input projections (merged): hu = xu@Wu^T+bu ; hr = xr@Wrec^T+brec
  {
    GParts P;
    P.A1[0] = xu_h; P.W1[0] = Wu_h;   P.A2[0] = nullptr; P.W2[0] = nullptr;
    P.bias[0] = bu;   P.out[0] = hu; P.M[0] = N_USERS;   P.np1[0] = 1; P.np2[0] = 0;
    P.relu[0] = 0; P.blk0[0] = 0;
    P.A1[1] = xr_h; P.W1[1] = Wrec_h; P.A2[1] = nullptr; P.W2[1] = nullptr;
    P.bias[1] = brec; P.out[1] = hr; P.M[1] = N_RECIPES; P.np1[1] = 2; P.np2[1] = 0;
    P.relu[1] = 0; P.blk0[1] = 782;
    clear_parts(P, 2);
    gemm_parts<128><<<782 + 391, 256, 0, stream>>>(P);
  }

  // ---- 7. conv1 recipe-side aggregation (mean-first)
  agg_mean2<H, false, false><<<(N_RECIPES * 16 + 255) / 256, 256, 0, stream>>>(
      hu, off_r, eidx_r, meanr, N_RECIPES);

  // ---- 8. conv1 (3 GEMMs merged): r1 = relu(meanr@Wl + hr@Wr + b) ;
  //          t_r1 = hr@c1ruWl ; u1 = hu@c1ruWr + b
  {
    GParts P;
    P.A1[0] = meanr; P.W1[0] = c1urWl_h; P.A2[0] = hr; P.W2[0] = c1urWr_h;
    P.bias[0] = c1_ur_bl; P.out[0] = r1; P.M[0] = N_RECIPES;
    P.np1[0] = 1; P.np2[0] = 1; P.relu[0] = 1; P.blk0[0] = 0;
    P.A1[1] = hr; P.W1[1] = c1ruWl_h; P.A2[1] = nullptr; P.W2[1] = nullptr;
    P.bias[1] = nullptr; P.out[1] = t_r1; P.M[1] = N_RECIPES;
    P.np1[1] = 1; P.np2[1] = 0; P.relu[1] = 0; P.blk0[1] = 391;
    P.A1[2] = hu; P.W1[2] = c1ruWr_h; P.A2[2] = nullptr; P.W2[2] = nullptr;
    P.bias[2] = c1_ru_bl; P.out[2] = u1; P.M[2] = N_USERS;
    P.np1[2] = 1; P.np2[2] = 0; P.relu[2] = 0; P.blk0[2] = 782;
    clear_parts(P, 3);
    gemm_parts<128><<<391 + 391 + 782, 256, 0, stream>>>(P);
  }
  // ---- 9. conv1 user-side aggregation: u1 = relu(u1 + mean(t_r1))
  agg_mean2<H, true, true><<<(N_USERS * 16 + 255) / 256, 256, 0, stream>>>(
      t_r1, off_u, eidx_u, u1, N_USERS);

  // ---- 10. conv2 transforms (4 GEMMs merged, BN=64/BM=256)
  {
    GParts P;
    P.A1[0] = u1; P.W1[0] = c2urWl_h; P.bias[0] = nullptr;  P.out[0] = t_u2;
    P.M[0] = N_USERS;   P.blk0[0] = 0;
    P.A1[1] = r1; P.W1[1] = c2urWr_h; P.bias[1] = c2_ur_bl; P.out[1] = zr;
    P.M[1] = N_RECIPES; P.blk0[1] = 391;
    P.A1[2] = r1; P.W1[2] = c2ruWl_h; P.bias[2] = nullptr;  P.out[2] = t_r2;
    P.M[2] = N_RECIPES; P.blk0[2] = 587;
    P.A1[3] = u1; P.W1[3] = c2ruWr_h; P.bias[3] = c2_ru_bl; P.out[3] = zu;
    P.M[3] = N_USERS;   P.blk0[3] = 783;
    for (int q = 0; q < 4; ++q) {
      P.A2[q] = nullptr; P.W2[q] = nullptr;
      P.np1[q] = 1; P.np2[q] = 0; P.relu[q] = 0;
    }
    gemm_parts<64><<<391 + 196 + 196 + 391, 256, 0, stream>>>(P);
  }
  // ---- 11. conv2 aggregations (merged): zr += mean(t_u2) ; zu += mean(t_r2)
  agg_mean_dual64<<<((N_RECIPES + N_USERS) * 8 + 255) / 256, 256, 0, stream>>>(
      t_u2, off_r, eidx_r, zr, t_r2, off_u, eidx_u, zu);

  // ---- 12. decoder
  decoder_f16<<<((size_t)NL * 64 + 255) / 256, 256, 0, stream>>>(zu, zr, lbl_src, lbl_dst, out);
}